// Round 2
// baseline (423.575 us; speedup 1.0000x reference)
//
#include <hip/hip_runtime.h>
#include <hip/hip_bf16.h>

#define NS 48
#define NV 10
#define NATT 78
#define HID 128
#define W1N 2304
#define W2N 480
#define W3N 100
#define W4N 480
#define WTOT 3364
#define NEDGE 50000
#define NNODE 10000
#define EPAD 50048       // 1564 * 32
#define EPSV 1e-5f
#define INV_SQRT3 0.57735026918962576f
#define NORM0 0.13130643285972254f   // 1/sqrt(58)
#define NORM1 0.13130643285972254f

// Fixed-point scales for deterministic integer accumulation
#define FXS  2147483648.0f           // 2^31  (edge contributions, first moment)
#define FXSI (1.0 / 2147483648.0)
#define FXQ  268435456.0f            // 2^28  (second moments)
#define FXQI (1.0 / 268435456.0)

// Repacked Bt2 column layout (tiles of 16 cols, 232 tiles = 3712 cols):
//  A: tiles   0..143  w1  c'=u*48+v            (u=t/3, v=16*(t%3)+col)
//  B: tiles 144..173  w4  c'=2304+u*48+v
//  C: tiles 174..221  w2  one u per tile, col=v (v<10 valid, rest zero-pad)
//  D: tiles 222..231  w3  one u per tile, col=v (v<10 valid)
#define CPAD2 3712
#define NT_A 144
#define NT_B 30
#define NT_C 48
#define NT_D 10

using short8 = __attribute__((ext_vector_type(8))) short;
using half8  = __attribute__((ext_vector_type(8))) _Float16;
using f32x4  = __attribute__((ext_vector_type(4))) float;

// fp16 (not bf16) for the second GEMM: 11-bit mantissa cuts rounding error ~8x
// at identical MFMA rate (mfma_f32_16x16x32_f16). Range safe: |h|<~8, |w2|<~1.
__device__ __forceinline__ unsigned short f2h(float x) {
  union { _Float16 h; unsigned short u; } v;
  v.h = (_Float16)x;            // RTN-even
  return v.u;
}

// Deterministic fixed-point atomic accumulate (integer adds are associative).
__device__ __forceinline__ void atomFx(unsigned long long* p, float x) {
  long long q = (long long)rintf(x * FXS);
  atomicAdd(p, (unsigned long long)q);
}

// ---------------- K0: fc_w2 (128 x 3364) -> Bt2 fp16 [CPAD2][128] + b2p ---------
__global__ __launch_bounds__(256) void k_prep_bt2(const float* __restrict__ w2,
                                                  const float* __restrict__ b2,
                                                  unsigned short* __restrict__ Bt2,
                                                  float* __restrict__ b2p) {
  int idx = blockIdx.x * 256 + threadIdx.x;   // CPAD2*128 total
  int cp = idx >> 7, k = idx & 127;
  int c_src = -1;
  if (cp < 2304)      c_src = cp;                                   // w1
  else if (cp < 2784) c_src = 2884 + (cp - 2304);                   // w4
  else if (cp < 3552) { int t = cp - 2784; int u = t >> 4, v = t & 15;
                        if (v < 10) c_src = 2304 + u * 10 + v; }    // w2
  else                { int t = cp - 3552; int u = t >> 4, v = t & 15;
                        if (v < 10) c_src = 2784 + u * 10 + v; }    // w3
  Bt2[idx] = (c_src >= 0) ? f2h(w2[(size_t)k * WTOT + c_src]) : (unsigned short)0;
  if (k == 0) b2p[cp] = (c_src >= 0) ? b2[c_src] : 0.f;
}

// ---------------- K1: h = relu(edge_attr @ fc_w1 + b1) -> fp16 [EPAD][128] ------
__global__ __launch_bounds__(256) void k_fc1(const float* __restrict__ ea,
                                             const float* __restrict__ w1,
                                             const float* __restrict__ b1,
                                             unsigned short* __restrict__ hbf) {
  __shared__ float sT[128][36];
  int tid = threadIdx.x;
  int e0 = blockIdx.x * 32;
  for (int i = tid; i < 32 * 128; i += 256) {
    int el = i >> 7, k = i & 127;
    int e = e0 + el;
    sT[k][el] = (e < NEDGE) ? ea[(size_t)e * 128 + k] : 0.f;
  }
  __syncthreads();
  int cg = tid & 31;
  int eg = tid >> 5;
  float acc[4][4] = {};
  #pragma unroll 4
  for (int k = 0; k < 128; ++k) {
    float4 a = *(const float4*)&sT[k][eg * 4];
    float4 w = *(const float4*)&w1[k * 128 + cg * 4];
    float av[4] = {a.x, a.y, a.z, a.w};
    float wv[4] = {w.x, w.y, w.z, w.w};
    #pragma unroll
    for (int ii = 0; ii < 4; ++ii)
      #pragma unroll
      for (int jj = 0; jj < 4; ++jj)
        acc[ii][jj] += av[ii] * wv[jj];
  }
  float bb[4];
  #pragma unroll
  for (int jj = 0; jj < 4; ++jj) bb[jj] = b1[cg * 4 + jj];
  #pragma unroll
  for (int ii = 0; ii < 4; ++ii) {
    int e = e0 + eg * 4 + ii;
    bool val = e < NEDGE;
    unsigned short h4[4];
    #pragma unroll
    for (int jj = 0; jj < 4; ++jj) {
      float r = val ? fmaxf(acc[ii][jj] + bb[jj], 0.f) : 0.f;
      h4[jj] = f2h(r);
    }
    uint2 pk;
    pk.x = (unsigned)h4[0] | ((unsigned)h4[1] << 16);
    pk.y = (unsigned)h4[2] | ((unsigned)h4[3] << 16);
    *(uint2*)(hbf + (size_t)e * 128 + cg * 4) = pk;
  }
}

// ---------------- K3: fused GEMM + tensor product, register epilogue ------------
__global__ __launch_bounds__(64, 2) void k_tp(const unsigned short* __restrict__ hbf,
                                              const unsigned short* __restrict__ Bt2,
                                              const float* __restrict__ b2p,
                                              const int* __restrict__ eidx,
                                              const float* __restrict__ node_attr,
                                              const float* __restrict__ esh,
                                              unsigned long long* __restrict__ summed,
                                              unsigned* __restrict__ cnt) {
  __shared__ float sF[32][49];     // pad 49: stride*4 != 0 mod 32 banks
  __shared__ float vF[32][30];
  __shared__ float dotN[32][10];   // dot * INV_SQRT3 * NORM0
  __shared__ float p0F[32], q0F[32];
  __shared__ float sh1nF[32][3];
  __shared__ int   srcL[32], dstL[32];

  int tid = threadIdx.x;           // 64 threads = 1 wave
  int e0 = blockIdx.x * 32;

  float s1x = 0.f, s1y = 0.f, s1z = 0.f;
  if (tid < 32) {
    int eg = e0 + tid;
    bool val = eg < NEDGE;
    srcL[tid] = val ? eidx[eg] : -1;
    dstL[tid] = val ? eidx[NEDGE + eg] : -1;
    float sh0 = 0.f;
    if (val) {
      float4 s4 = *(const float4*)&esh[(size_t)eg * 4];
      sh0 = s4.x; s1x = s4.y; s1y = s4.z; s1z = s4.w;
    }
    p0F[tid] = sh0 * NORM0;
    q0F[tid] = sh0 * NORM1;
    sh1nF[tid][0] = s1x * NORM1; sh1nF[tid][1] = s1y * NORM1; sh1nF[tid][2] = s1z * NORM1;
  }
  __syncthreads();
  for (int i = tid; i < 32 * NATT; i += 64) {
    int el = i / NATT, a = i % NATT;
    int dst = dstL[el];
    float x = (dst >= 0) ? node_attr[(size_t)dst * NATT + a] : 0.f;
    if (a < NS) sF[el][a] = x; else vF[el][a - NS] = x;
  }
  __syncthreads();
  if (tid < 32) {
    #pragma unroll
    for (int u = 0; u < NV; ++u)
      dotN[tid][u] = (vF[tid][u*3] * s1x + vF[tid][u*3+1] * s1y + vF[tid][u*3+2] * s1z)
                     * (INV_SQRT3 * NORM0);
  }
  __syncthreads();

  int quad = tid >> 4;
  int col  = tid & 15;
  int elq  = quad * 4;             // el = mt*16 + elq + r

  // A fragments in registers: 32 edges x K=128
  half8 aF[2][4];
  {
    const half8* hp = (const half8*)hbf;
    #pragma unroll
    for (int mt = 0; mt < 2; ++mt) {
      size_t row = (size_t)(e0 + mt * 16 + col) * 16;
      #pragma unroll
      for (int ks = 0; ks < 4; ++ks) aF[mt][ks] = hp[row + ks * 4 + quad];
    }
  }
  float p0v[2][4];
  #pragma unroll
  for (int mt = 0; mt < 2; ++mt)
    #pragma unroll
    for (int r = 0; r < 4; ++r) p0v[mt][r] = p0F[mt * 16 + elq + r];

  const half8* bp = (const half8*)Bt2;

  float acc0[2][4][3] = {};   // out0[el][16j+col]
  float t1a[2][4]     = {};   // sum_u w2[u,col]*s[u]   (col<10)
  float t3a[2][4][3]  = {};   // sum_u w3[u,col]*v[u][i]

  auto do_tile = [&](int t, f32x4& m0, f32x4& m1) {
    const half8* bb = bp + (size_t)(t * 16 + col) * 16 + quad;
    half8 b0 = bb[0], b1_ = bb[4], b2_ = bb[8], b3 = bb[12];
    f32x4 a0 = {0.f,0.f,0.f,0.f}, a1 = {0.f,0.f,0.f,0.f};
    a0 = __builtin_amdgcn_mfma_f32_16x16x32_f16(aF[0][0], b0,  a0, 0, 0, 0);
    a0 = __builtin_amdgcn_mfma_f32_16x16x32_f16(aF[0][1], b1_, a0, 0, 0, 0);
    a0 = __builtin_amdgcn_mfma_f32_16x16x32_f16(aF[0][2], b2_, a0, 0, 0, 0);
    a0 = __builtin_amdgcn_mfma_f32_16x16x32_f16(aF[0][3], b3,  a0, 0, 0, 0);
    a1 = __builtin_amdgcn_mfma_f32_16x16x32_f16(aF[1][0], b0,  a1, 0, 0, 0);
    a1 = __builtin_amdgcn_mfma_f32_16x16x32_f16(aF[1][1], b1_, a1, 0, 0, 0);
    a1 = __builtin_amdgcn_mfma_f32_16x16x32_f16(aF[1][2], b2_, a1, 0, 0, 0);
    a1 = __builtin_amdgcn_mfma_f32_16x16x32_f16(aF[1][3], b3,  a1, 0, 0, 0);
    m0 = a0; m1 = a1;
  };

  // ---- Region A: w1, 48 u-groups x 3 tiles ----
  #pragma unroll 1
  for (int u = 0; u < 48; ++u) {
    float sfac[2][4];
    #pragma unroll
    for (int mt = 0; mt < 2; ++mt)
      #pragma unroll
      for (int r = 0; r < 4; ++r)
        sfac[mt][r] = sF[mt * 16 + elq + r][u] * p0v[mt][r];
    #pragma unroll
    for (int j = 0; j < 3; ++j) {
      int t = u * 3 + j;
      float b2c = b2p[t * 16 + col];
      f32x4 m0, m1;
      do_tile(t, m0, m1);
      #pragma unroll
      for (int r = 0; r < 4; ++r) {
        acc0[0][r][j] += (m0[r] + b2c) * sfac[0][r];
        acc0[1][r][j] += (m1[r] + b2c) * sfac[1][r];
      }
    }
  }
  // ---- Region B: w4, 10 u-groups x 3 tiles ----
  #pragma unroll 1
  for (int u = 0; u < 10; ++u) {
    float dfac[2][4];
    #pragma unroll
    for (int mt = 0; mt < 2; ++mt)
      #pragma unroll
      for (int r = 0; r < 4; ++r)
        dfac[mt][r] = dotN[mt * 16 + elq + r][u];
    #pragma unroll
    for (int j = 0; j < 3; ++j) {
      int t = NT_A + u * 3 + j;
      float b2c = b2p[t * 16 + col];
      f32x4 m0, m1;
      do_tile(t, m0, m1);
      #pragma unroll
      for (int r = 0; r < 4; ++r) {
        acc0[0][r][j] += (m0[r] + b2c) * dfac[0][r];
        acc0[1][r][j] += (m1[r] + b2c) * dfac[1][r];
      }
    }
  }
  // ---- Region C: w2, 48 tiles (one u each), col = v ----
  #pragma unroll 2
  for (int u = 0; u < 48; ++u) {
    int t = NT_A + NT_B + u;
    float b2c = b2p[t * 16 + col];
    float sc[2][4];
    #pragma unroll
    for (int mt = 0; mt < 2; ++mt)
      #pragma unroll
      for (int r = 0; r < 4; ++r)
        sc[mt][r] = sF[mt * 16 + elq + r][u];
    f32x4 m0, m1;
    do_tile(t, m0, m1);
    #pragma unroll
    for (int r = 0; r < 4; ++r) {
      t1a[0][r] += (m0[r] + b2c) * sc[0][r];
      t1a[1][r] += (m1[r] + b2c) * sc[1][r];
    }
  }
  // ---- Region D: w3, 10 tiles (one u each), col = v ----
  #pragma unroll 1
  for (int u = 0; u < 10; ++u) {
    int t = NT_A + NT_B + NT_C + u;
    float b2c = b2p[t * 16 + col];
    f32x4 m0, m1;
    do_tile(t, m0, m1);
    #pragma unroll
    for (int mt = 0; mt < 2; ++mt)
      #pragma unroll
      for (int r = 0; r < 4; ++r) {
        float w = (mt == 0 ? m0[r] : m1[r]) + b2c;
        int el = mt * 16 + elq + r;
        #pragma unroll
        for (int i = 0; i < 3; ++i)
          t3a[mt][r][i] += w * vF[el][u * 3 + i];
      }
  }

  // ---- Flush: registers -> global integer atomics (deterministic) ----
  #pragma unroll
  for (int mt = 0; mt < 2; ++mt)
    #pragma unroll
    for (int r = 0; r < 4; ++r) {
      int el = mt * 16 + elq + r;
      int src = srcL[el];
      if (src < 0) continue;
      unsigned long long* dp = &summed[(size_t)src * NATT];
      #pragma unroll
      for (int j = 0; j < 3; ++j)
        atomFx(dp + j * 16 + col, acc0[mt][r][j]);
      if (col < 10) {
        float q0 = q0F[el];
        #pragma unroll
        for (int i = 0; i < 3; ++i)
          atomFx(dp + NS + col * 3 + i,
                 t1a[mt][r] * sh1nF[el][i] + t3a[mt][r][i] * q0);
      }
    }
  if (tid < 32 && srcL[tid] >= 0) atomicAdd(&cnt[srcL[tid]], 1u);
}

// ---------------- K4: mean over segment + residual, accumulate BN stats ---------
__global__ __launch_bounds__(256) void k_node(const unsigned long long* __restrict__ summed,
                                              const unsigned* __restrict__ cnt,
                                              const float* __restrict__ node_attr,
                                              float* __restrict__ outp,
                                              unsigned long long* __restrict__ stats) {
  __shared__ unsigned long long ls[NS], lq[NS], lv[NV];
  int tid = threadIdx.x;
  if (tid < NS) { ls[tid] = 0ull; lq[tid] = 0ull; }
  if (tid < NV) lv[tid] = 0ull;
  __syncthreads();
  int i = blockIdx.x * 256 + tid;
  if (i < NNODE * NATT) {
    int row = i / NATT, colc = i % NATT;
    long long sv = (long long)summed[i];
    float sum = (float)((double)sv * FXSI);
    float x = sum / fmaxf((float)cnt[row], 1.f) + node_attr[i];
    outp[i] = x;
    if (colc < NS) {
      atomicAdd(&ls[colc], (unsigned long long)(long long)rintf(x * FXS));
      atomicAdd(&lq[colc], (unsigned long long)(long long)rintf(x * x * FXQ));
    } else {
      atomicAdd(&lv[(colc - NS) / 3], (unsigned long long)(long long)rintf(x * x * FXQ));
    }
  }
  __syncthreads();
  if (tid < NS) { atomicAdd(&stats[tid], ls[tid]); atomicAdd(&stats[NS + tid], lq[tid]); }
  if (tid < NV) atomicAdd(&stats[96 + tid], lv[tid]);
}

// ---------------- K5: batch norm apply ------------------------------------------
__global__ __launch_bounds__(256) void k_bn(const float* __restrict__ outp,
                                            const unsigned long long* __restrict__ stats,
                                            const float* __restrict__ bnw,
                                            const float* __restrict__ bnb,
                                            float* __restrict__ out) {
  int i = blockIdx.x * 256 + threadIdx.x;
  if (i >= NNODE * NATT) return;
  int colc = i % NATT;
  float x = outp[i];
  float r;
  if (colc < NS) {
    float mean = (float)((double)(long long)stats[colc] * (FXSI / NNODE));
    float ex2  = (float)((double)(long long)stats[NS + colc] * (FXQI / NNODE));
    float var  = ex2 - mean * mean;
    r = (x - mean) * rsqrtf(var + EPSV) * bnw[colc] + bnb[colc];
  } else {
    int u = (colc - NS) / 3;
    float vn = (float)((double)(long long)stats[96 + u] * (FXQI / (3.0 * NNODE)));
    r = x * rsqrtf(vn + EPSV) * bnw[NS + u];
  }
  out[i] = r;
}

extern "C" void kernel_launch(void* const* d_in, const int* in_sizes, int n_in,
                              void* d_out, int out_size, void* d_ws, size_t ws_size,
                              hipStream_t stream) {
  const float* node_attr = (const float*)d_in[0];
  const int*   eidx      = (const int*)d_in[1];
  const float* edge_attr = (const float*)d_in[2];
  const float* esh       = (const float*)d_in[3];
  const float* fw1       = (const float*)d_in[4];
  const float* fb1       = (const float*)d_in[5];
  const float* fw2       = (const float*)d_in[6];
  const float* fb2       = (const float*)d_in[7];
  const float* bnw       = (const float*)d_in[8];
  const float* bnb       = (const float*)d_in[9];
  float* out = (float*)d_out;

  char* ws = (char*)d_ws;
  // layout (bytes):
  //   Bt2    @ 0        : CPAD2*128*2 =    950,272   (dead after k_tp)
  //   b2p    @ 950272   : CPAD2*4     =     14,848   (dead after k_tp)
  //   hbf    @ 965120   : EPAD*128*2  = 12,812,288   (dead after k_tp)
  //   summed @ 13777408 : N*78*8      =  6,240,000   (i64 Q31)
  //   cnt    @ 20017408 : N*4         =     40,000   (u32)
  //   outp   @ 0        : N*78*4      =  3,120,000   (reuses Bt2 region, after k_tp)
  //   stats  @ 3120000  : 128*8       =      1,024   (reuses hbf region, after k_tp)
  //   total  20,057,408
  unsigned short*     Bt2    = (unsigned short*)(ws + 0);
  float*              b2p    = (float*)(ws + 950272);
  unsigned short*     hbf    = (unsigned short*)(ws + 965120);
  unsigned long long* summed = (unsigned long long*)(ws + 13777408);
  unsigned*           cnt    = (unsigned*)(ws + 20017408);
  float*              outp   = (float*)(ws + 0);
  unsigned long long* stats  = (unsigned long long*)(ws + 3120000);

  hipMemsetAsync(ws + 13777408, 0, 6240000 + 40000, stream);   // summed + cnt

  k_prep_bt2<<<(CPAD2 * 128) / 256, 256, 0, stream>>>(fw2, fb2, Bt2, b2p);
  k_fc1<<<EPAD / 32, 256, 0, stream>>>(edge_attr, fw1, fb1, hbf);
  k_tp<<<EPAD / 32, 64, 0, stream>>>(hbf, Bt2, b2p, eidx, node_attr, esh, summed, cnt);
  // stats region lives inside the (now-dead) hbf area; zero it after k_tp.
  hipMemsetAsync(ws + 3120000, 0, 1024, stream);
  int nelem_blocks = (NNODE * NATT + 255) / 256;
  k_node<<<nelem_blocks, 256, 0, stream>>>(summed, cnt, node_attr, outp, stats);
  k_bn<<<nelem_blocks, 256, 0, stream>>>(outp, stats, bnw, bnb, out);
}

// Round 3
// 392.020 us; speedup vs baseline: 1.0805x; 1.0805x over previous
//
#include <hip/hip_runtime.h>
#include <hip/hip_bf16.h>

#define NS 48
#define NV 10
#define NATT 78
#define HID 128
#define W1N 2304
#define W2N 480
#define W3N 100
#define W4N 480
#define WTOT 3364
#define NEDGE 50000
#define NNODE 10000
#define EPAD 50048       // 782 * 64
#define EPSV 1e-5f
#define INV_SQRT3 0.57735026918962576f
#define NORM0 0.13130643285972254f   // 1/sqrt(58)
#define NORM1 0.13130643285972254f

// Fixed-point scales for deterministic integer accumulation
#define FXS  2147483648.0f           // 2^31  (edge contributions, first moment)
#define FXSI (1.0 / 2147483648.0)
#define FXQ  268435456.0f            // 2^28  (second moments)
#define FXQI (1.0 / 268435456.0)

// Repacked Bt2 column layout (tiles of 16 cols, 232 tiles = 3712 cols):
//  A: tiles   0..143  w1  c'=u*48+v            (u=t/3, v=16*(t%3)+col)
//  B: tiles 144..173  w4  c'=2304+u*48+v
//  C: tiles 174..221  w2  one u per tile, col=v (v<10 valid, rest zero-pad)
//  D: tiles 222..231  w3  one u per tile, col=v (v<10 valid)
#define CPAD2 3712
#define NT_A 144
#define NT_B 30
#define NT_C 48
#define NT_D 10
#define NTILE 232

using half8 = __attribute__((ext_vector_type(8))) _Float16;
using f32x4 = __attribute__((ext_vector_type(4))) float;

// fp16 for the second GEMM: 11-bit mantissa, same MFMA rate as bf16.
__device__ __forceinline__ unsigned short f2h(float x) {
  union { _Float16 h; unsigned short u; } v;
  v.h = (_Float16)x;            // RTN-even
  return v.u;
}

// Deterministic fixed-point atomic accumulate (integer adds are associative).
__device__ __forceinline__ void atomFx(unsigned long long* p, float x) {
  long long q = (long long)rintf(x * FXS);
  atomicAdd(p, (unsigned long long)q);
}

// ---------------- K0: fc_w2 (128 x 3364) -> Bt2 fp16 [CPAD2][128] + b2p ---------
__global__ __launch_bounds__(256) void k_prep_bt2(const float* __restrict__ w2,
                                                  const float* __restrict__ b2,
                                                  unsigned short* __restrict__ Bt2,
                                                  float* __restrict__ b2p) {
  int idx = blockIdx.x * 256 + threadIdx.x;   // CPAD2*128 total
  int cp = idx >> 7, k = idx & 127;
  int c_src = -1;
  if (cp < 2304)      c_src = cp;                                   // w1
  else if (cp < 2784) c_src = 2884 + (cp - 2304);                   // w4
  else if (cp < 3552) { int t = cp - 2784; int u = t >> 4, v = t & 15;
                        if (v < 10) c_src = 2304 + u * 10 + v; }    // w2
  else                { int t = cp - 3552; int u = t >> 4, v = t & 15;
                        if (v < 10) c_src = 2784 + u * 10 + v; }    // w3
  Bt2[idx] = (c_src >= 0) ? f2h(w2[(size_t)k * WTOT + c_src]) : (unsigned short)0;
  if (k == 0) b2p[cp] = (c_src >= 0) ? b2[c_src] : 0.f;
}

// ---------------- K1: h = relu(edge_attr @ fc_w1 + b1) -> fp16 [EPAD][128] ------
__global__ __launch_bounds__(256) void k_fc1(const float* __restrict__ ea,
                                             const float* __restrict__ w1,
                                             const float* __restrict__ b1,
                                             unsigned short* __restrict__ hbf) {
  __shared__ float sT[128][36];
  int tid = threadIdx.x;
  int e0 = blockIdx.x * 32;
  for (int i = tid; i < 32 * 128; i += 256) {
    int el = i >> 7, k = i & 127;
    int e = e0 + el;
    sT[k][el] = (e < NEDGE) ? ea[(size_t)e * 128 + k] : 0.f;
  }
  __syncthreads();
  int cg = tid & 31;
  int eg = tid >> 5;
  float acc[4][4] = {};
  #pragma unroll 4
  for (int k = 0; k < 128; ++k) {
    float4 a = *(const float4*)&sT[k][eg * 4];
    float4 w = *(const float4*)&w1[k * 128 + cg * 4];
    float av[4] = {a.x, a.y, a.z, a.w};
    float wv[4] = {w.x, w.y, w.z, w.w};
    #pragma unroll
    for (int ii = 0; ii < 4; ++ii)
      #pragma unroll
      for (int jj = 0; jj < 4; ++jj)
        acc[ii][jj] += av[ii] * wv[jj];
  }
  float bb[4];
  #pragma unroll
  for (int jj = 0; jj < 4; ++jj) bb[jj] = b1[cg * 4 + jj];
  #pragma unroll
  for (int ii = 0; ii < 4; ++ii) {
    int e = e0 + eg * 4 + ii;
    bool val = e < NEDGE;
    unsigned short h4[4];
    #pragma unroll
    for (int jj = 0; jj < 4; ++jj) {
      float r = val ? fmaxf(acc[ii][jj] + bb[jj], 0.f) : 0.f;
      h4[jj] = f2h(r);
    }
    uint2 pk;
    pk.x = (unsigned)h4[0] | ((unsigned)h4[1] << 16);
    pk.y = (unsigned)h4[2] | ((unsigned)h4[3] << 16);
    *(uint2*)(hbf + (size_t)e * 128 + cg * 4) = pk;
  }
}

// ---------------- K3: fused GEMM + tensor product -------------------------------
// 4 waves/block, 64 edges/block (wave w owns edges w*16..w*16+15, full K=128).
// B tiles staged once per block into LDS via global_load_lds (16B/lane),
// 3-buffer pipeline with counted vmcnt(2) + raw s_barrier (no vmcnt(0) drain).
__global__ __launch_bounds__(256, 3) void k_tp(const unsigned short* __restrict__ hbf,
                                               const unsigned short* __restrict__ Bt2,
                                               const float* __restrict__ b2p,
                                               const int* __restrict__ eidx,
                                               const float* __restrict__ node_attr,
                                               const float* __restrict__ esh,
                                               unsigned long long* __restrict__ summed,
                                               unsigned* __restrict__ cnt) {
  __shared__ half8 bufB[3][256];        // 3 x 4KB staged B tiles
  __shared__ float b2pL[CPAD2];         // 14848 B
  __shared__ float sFL[64][49];
  __shared__ float vFL[64][30];
  __shared__ float dotNL[64][10];
  __shared__ float p0FL[64], q0FL[64];
  __shared__ float sh1nL[64][3];
  __shared__ int   srcL[64], dstL[64];

  const int tid  = threadIdx.x;
  const int wid  = tid >> 6;           // wave id 0..3
  const int lane = tid & 63;
  const int col  = lane & 15;
  const int quad = lane >> 4;
  const int e0   = blockIdx.x * 64;
  const int elb  = wid * 16 + quad * 4; // local edge base for this lane's rows

  float s1x = 0.f, s1y = 0.f, s1z = 0.f;
  if (tid < 64) {
    int eg = e0 + tid;
    bool val = eg < NEDGE;
    srcL[tid] = val ? eidx[eg] : -1;
    dstL[tid] = val ? eidx[NEDGE + eg] : -1;
    float sh0 = 0.f;
    if (val) {
      float4 s4 = *(const float4*)&esh[(size_t)eg * 4];
      sh0 = s4.x; s1x = s4.y; s1y = s4.z; s1z = s4.w;
    }
    p0FL[tid] = sh0 * NORM0;
    q0FL[tid] = sh0 * NORM1;
    sh1nL[tid][0] = s1x * NORM1; sh1nL[tid][1] = s1y * NORM1; sh1nL[tid][2] = s1z * NORM1;
  }
  for (int i = tid; i < CPAD2; i += 256) b2pL[i] = b2p[i];
  __syncthreads();
  for (int i = tid; i < 64 * NATT; i += 256) {
    int el = i / NATT, a = i % NATT;
    int dst = dstL[el];
    float x = (dst >= 0) ? node_attr[(size_t)dst * NATT + a] : 0.f;
    if (a < NS) sFL[el][a] = x; else vFL[el][a - NS] = x;
  }
  __syncthreads();
  if (tid < 64) {
    #pragma unroll
    for (int u = 0; u < NV; ++u)
      dotNL[tid][u] = (vFL[tid][u*3] * s1x + vFL[tid][u*3+1] * s1y + vFL[tid][u*3+2] * s1z)
                      * (INV_SQRT3 * NORM0);
  }
  __syncthreads();

  // A fragments for this wave's 16 edges (full K=128)
  half8 aF[4];
  {
    const half8* hp = (const half8*)hbf;
    size_t arow = (size_t)(e0 + wid * 16 + col) * 16;
    #pragma unroll
    for (int ks = 0; ks < 4; ++ks) aF[ks] = hp[arow + ks * 4 + quad];
  }
  float p0v[4];
  #pragma unroll
  for (int r = 0; r < 4; ++r) p0v[r] = p0FL[elb + r];

  // ---- staging: dest slot = tid (LDS linear), source pre-swizzled (m173) ----
  // LDS[col][k8] = Bt2[tile][col][k8 ^ (col&15)]; reader XORs the same way.
  const char* bt2c = (const char*)Bt2;
  const int colS = tid >> 4, k8sS = tid & 15;
  const size_t gOff = (size_t)(colS * 16 + (k8sS ^ colS)) * 16;

  #define STAGE(T, bi)                                                            \
    __builtin_amdgcn_global_load_lds(                                             \
      (const __attribute__((address_space(1))) void*)(bt2c + (size_t)(T) * 4096 + gOff), \
      (__attribute__((address_space(3))) void*)((char*)&bufB[(bi)][0] + wid * 1024),     \
      16, 0, 0)

  #define PIPE_HEAD() do {                                          \
    asm volatile("s_waitcnt vmcnt(2)" ::: "memory");                \
    __builtin_amdgcn_s_barrier();                                   \
  } while (0)
  #define PIPE_TAIL(Tn, bi) do {                                    \
    asm volatile("s_waitcnt lgkmcnt(0)" ::: "memory");              \
    __builtin_amdgcn_s_barrier();                                   \
    STAGE((Tn), (bi));                                              \
  } while (0)

  STAGE(0, 0); STAGE(1, 1); STAGE(2, 2);

  float acc0[4][3] = {};
  float t1a[4] = {};
  float t3a[4][3] = {};

  auto MFMA4 = [&](int bi) -> f32x4 {
    f32x4 m = {0.f, 0.f, 0.f, 0.f};
    #pragma unroll
    for (int ks = 0; ks < 4; ++ks) {
      half8 b = bufB[bi][col * 16 + ((ks * 4 + quad) ^ col)];
      m = __builtin_amdgcn_mfma_f32_16x16x32_f16(aF[ks], b, m, 0, 0, 0);
    }
    return m;
  };

  // ---- Region A: w1, 48 u-groups x 3 tiles (T = u*3+j, bi = j) ----
  #pragma unroll 1
  for (int u = 0; u < 48; ++u) {
    float sfac[4];
    #pragma unroll
    for (int r = 0; r < 4; ++r) sfac[r] = sFL[elb + r][u] * p0v[r];
    #pragma unroll
    for (int j = 0; j < 3; ++j) {
      int T = u * 3 + j;
      PIPE_HEAD();
      float b2c = b2pL[T * 16 + col];
      f32x4 m = MFMA4(j);
      PIPE_TAIL(T + 3, j);
      #pragma unroll
      for (int r = 0; r < 4; ++r) acc0[r][j] += (m[r] + b2c) * sfac[r];
    }
  }
  // ---- Region B: w4, 10 u-groups x 3 tiles ----
  #pragma unroll 1
  for (int u = 0; u < 10; ++u) {
    float dfac[4];
    #pragma unroll
    for (int r = 0; r < 4; ++r) dfac[r] = dotNL[elb + r][u];
    #pragma unroll
    for (int j = 0; j < 3; ++j) {
      int T = NT_A + u * 3 + j;
      PIPE_HEAD();
      float b2c = b2pL[T * 16 + col];
      f32x4 m = MFMA4(j);
      PIPE_TAIL(T + 3, j);
      #pragma unroll
      for (int r = 0; r < 4; ++r) acc0[r][j] += (m[r] + b2c) * dfac[r];
    }
  }
  // ---- Region C: w2, 48 tiles (T = 174+u, bi = u%3) ----
  #pragma unroll 1
  for (int u = 0; u < 48; ++u) {
    int T = NT_A + NT_B + u;
    int bi = u % 3;
    PIPE_HEAD();
    float b2c = b2pL[T * 16 + col];
    float sc[4];
    #pragma unroll
    for (int r = 0; r < 4; ++r) sc[r] = sFL[elb + r][u];
    f32x4 m = MFMA4(bi);
    PIPE_TAIL(T + 3, bi);
    #pragma unroll
    for (int r = 0; r < 4; ++r) t1a[r] += (m[r] + b2c) * sc[r];
  }
  // ---- Region D: w3, 10 tiles (T = 222+u, bi = u%3), tail-peeled ----
  auto computeD = [&](int u, int bi) {
    int T = NT_A + NT_B + NT_C + u;
    float b2c = b2pL[T * 16 + col];
    f32x4 m = MFMA4(bi);
    #pragma unroll
    for (int r = 0; r < 4; ++r) {
      float w = m[r] + b2c;
      int el = elb + r;
      #pragma unroll
      for (int i = 0; i < 3; ++i) t3a[r][i] += w * vFL[el][u * 3 + i];
    }
  };
  #pragma unroll 1
  for (int u = 0; u < 7; ++u) {          // T=222..228, stage 225..231
    int bi = u % 3;
    PIPE_HEAD();
    computeD(u, bi);
    PIPE_TAIL(NT_A + NT_B + NT_C + u + 3, bi);
  }
  { asm volatile("s_waitcnt vmcnt(2)" ::: "memory"); __builtin_amdgcn_s_barrier();
    computeD(7, 1); }
  { asm volatile("s_waitcnt vmcnt(1)" ::: "memory"); __builtin_amdgcn_s_barrier();
    computeD(8, 2); }
  { asm volatile("s_waitcnt vmcnt(0)" ::: "memory"); __builtin_amdgcn_s_barrier();
    computeD(9, 0); }

  // ---- Flush: registers -> global integer atomics (deterministic) ----
  #pragma unroll
  for (int r = 0; r < 4; ++r) {
    int el = elb + r;
    int src = srcL[el];
    if (src < 0) continue;
    unsigned long long* dp = &summed[(size_t)src * NATT];
    #pragma unroll
    for (int j = 0; j < 3; ++j)
      atomFx(dp + j * 16 + col, acc0[r][j]);
    if (col < 10) {
      float q0 = q0FL[el];
      #pragma unroll
      for (int i = 0; i < 3; ++i)
        atomFx(dp + NS + col * 3 + i,
               t1a[r] * sh1nL[el][i] + t3a[r][i] * q0);
    }
  }
  if (tid < 64 && srcL[tid] >= 0) atomicAdd(&cnt[srcL[tid]], 1u);
  #undef STAGE
  #undef PIPE_HEAD
  #undef PIPE_TAIL
}

// ---------------- K4: mean over segment + residual, accumulate BN stats ---------
__global__ __launch_bounds__(256) void k_node(const unsigned long long* __restrict__ summed,
                                              const unsigned* __restrict__ cnt,
                                              const float* __restrict__ node_attr,
                                              float* __restrict__ outp,
                                              unsigned long long* __restrict__ stats) {
  __shared__ unsigned long long ls[NS], lq[NS], lv[NV];
  int tid = threadIdx.x;
  if (tid < NS) { ls[tid] = 0ull; lq[tid] = 0ull; }
  if (tid < NV) lv[tid] = 0ull;
  __syncthreads();
  int i = blockIdx.x * 256 + tid;
  if (i < NNODE * NATT) {
    int row = i / NATT, colc = i % NATT;
    long long sv = (long long)summed[i];
    float sum = (float)((double)sv * FXSI);
    float x = sum / fmaxf((float)cnt[row], 1.f) + node_attr[i];
    outp[i] = x;
    if (colc < NS) {
      atomicAdd(&ls[colc], (unsigned long long)(long long)rintf(x * FXS));
      atomicAdd(&lq[colc], (unsigned long long)(long long)rintf(x * x * FXQ));
    } else {
      atomicAdd(&lv[(colc - NS) / 3], (unsigned long long)(long long)rintf(x * x * FXQ));
    }
  }
  __syncthreads();
  if (tid < NS) { atomicAdd(&stats[tid], ls[tid]); atomicAdd(&stats[NS + tid], lq[tid]); }
  if (tid < NV) atomicAdd(&stats[96 + tid], lv[tid]);
}

// ---------------- K5: batch norm apply ------------------------------------------
__global__ __launch_bounds__(256) void k_bn(const float* __restrict__ outp,
                                            const unsigned long long* __restrict__ stats,
                                            const float* __restrict__ bnw,
                                            const float* __restrict__ bnb,
                                            float* __restrict__ out) {
  int i = blockIdx.x * 256 + threadIdx.x;
  if (i >= NNODE * NATT) return;
  int colc = i % NATT;
  float x = outp[i];
  float r;
  if (colc < NS) {
    float mean = (float)((double)(long long)stats[colc] * (FXSI / NNODE));
    float ex2  = (float)((double)(long long)stats[NS + colc] * (FXQI / NNODE));
    float var  = ex2 - mean * mean;
    r = (x - mean) * rsqrtf(var + EPSV) * bnw[colc] + bnb[colc];
  } else {
    int u = (colc - NS) / 3;
    float vn = (float)((double)(long long)stats[96 + u] * (FXQI / (3.0 * NNODE)));
    r = x * rsqrtf(vn + EPSV) * bnw[NS + u];
  }
  out[i] = r;
}

extern "C" void kernel_launch(void* const* d_in, const int* in_sizes, int n_in,
                              void* d_out, int out_size, void* d_ws, size_t ws_size,
                              hipStream_t stream) {
  const float* node_attr = (const float*)d_in[0];
  const int*   eidx      = (const int*)d_in[1];
  const float* edge_attr = (const float*)d_in[2];
  const float* esh       = (const float*)d_in[3];
  const float* fw1       = (const float*)d_in[4];
  const float* fb1       = (const float*)d_in[5];
  const float* fw2       = (const float*)d_in[6];
  const float* fb2       = (const float*)d_in[7];
  const float* bnw       = (const float*)d_in[8];
  const float* bnb       = (const float*)d_in[9];
  float* out = (float*)d_out;

  char* ws = (char*)d_ws;
  // layout (bytes):
  //   Bt2    @ 0        : CPAD2*128*2 =    950,272   (dead after k_tp)
  //   b2p    @ 950272   : CPAD2*4     =     14,848   (dead after k_tp)
  //   hbf    @ 965120   : EPAD*128*2  = 12,812,288   (dead after k_tp)
  //   summed @ 13777408 : N*78*8      =  6,240,000   (i64 Q31)
  //   cnt    @ 20017408 : N*4         =     40,000   (u32)
  //   outp   @ 0        : N*78*4      =  3,120,000   (reuses Bt2 region, after k_tp)
  //   stats  @ 3120000  : 128*8       =      1,024   (reuses hbf region, after k_tp)
  unsigned short*     Bt2    = (unsigned short*)(ws + 0);
  float*              b2p    = (float*)(ws + 950272);
  unsigned short*     hbf    = (unsigned short*)(ws + 965120);
  unsigned long long* summed = (unsigned long long*)(ws + 13777408);
  unsigned*           cnt    = (unsigned*)(ws + 20017408);
  float*              outp   = (float*)(ws + 0);
  unsigned long long* stats  = (unsigned long long*)(ws + 3120000);

  hipMemsetAsync(ws + 13777408, 0, 6240000 + 40000, stream);   // summed + cnt

  k_prep_bt2<<<(CPAD2 * 128) / 256, 256, 0, stream>>>(fw2, fb2, Bt2, b2p);
  k_fc1<<<EPAD / 32, 256, 0, stream>>>(edge_attr, fw1, fb1, hbf);
  k_tp<<<EPAD / 64, 256, 0, stream>>>(hbf, Bt2, b2p, eidx, node_attr, esh, summed, cnt);
  hipMemsetAsync(ws + 3120000, 0, 1024, stream);
  int nelem_blocks = (NNODE * NATT + 255) / 256;
  k_node<<<nelem_blocks, 256, 0, stream>>>(summed, cnt, node_attr, outp, stats);
  k_bn<<<nelem_blocks, 256, 0, stream>>>(outp, stats, bnw, bnb, out);
}

// Round 8
// 372.258 us; speedup vs baseline: 1.1379x; 1.0531x over previous
//
#include <hip/hip_runtime.h>
#include <hip/hip_bf16.h>

#define NS 48
#define NV 10
#define NATT 78
#define HID 128
#define WTOT 3364
#define NEDGE 50000
#define NNODE 10000
#define EPAD 50048       // 782 * 64
#define EPSV 1e-5f
#define INV_SQRT3 0.57735026918962576f
#define NORM0 0.13130643285972254f   // 1/sqrt(58)
#define NORM1 0.13130643285972254f

// Fixed-point scales for deterministic integer accumulation
#define FXS  2147483648.0f           // 2^31
#define FXSI (1.0 / 2147483648.0)
#define FXQ  268435456.0f            // 2^28
#define FXQI (1.0 / 268435456.0)

// Repacked Bt2 column layout (tiles of 16 cols; 232 real + 2 pad = 234 tiles):
//  A: tiles   0..143  w1  (u=t/3, v=16*(t%3)+col)
//  B: tiles 144..173  w4
//  C: tiles 174..221  w2  one u per tile, col=v (v<10 valid)
//  D: tiles 222..231  w3  one u per tile, col=v (v<10 valid)
//  pad: 232..233 zero
#define CPAD2 3744
#define NTILE 232
#define NGRP  78          // 78 groups x 3 tiles

using half8 = __attribute__((ext_vector_type(8))) _Float16;
using f32x4 = __attribute__((ext_vector_type(4))) float;

__device__ __forceinline__ unsigned short f2h(float x) {
  union { _Float16 h; unsigned short u; } v;
  v.h = (_Float16)x;
  return v.u;
}

__device__ __forceinline__ void atomFx(unsigned long long* p, float x) {
  long long q = (long long)rintf(x * FXS);
  atomicAdd(p, (unsigned long long)q);
}

// cp (repacked col) -> source col in fc_w2/fc_b2, or -1 for zero-pad
__device__ __forceinline__ int cp_to_src(int cp) {
  if (cp < 2304) return cp;                                         // w1
  if (cp < 2784) return 2884 + (cp - 2304);                         // w4
  if (cp < 3552) { int t = cp - 2784; int u = t >> 4, v = t & 15;
                   return (v < 10) ? (2304 + u * 10 + v) : -1; }    // w2
  if (cp < 3712) { int t = cp - 3552; int u = t >> 4, v = t & 15;
                   return (v < 10) ? (2784 + u * 10 + v) : -1; }    // w3
  return -1;                                                        // pad tiles
}

// ---------------- K0: fc_w2 (128 x 3364) -> Bt2 fp16 [CPAD2][128] ---------------
__global__ __launch_bounds__(256) void k_prep_bt2(const float* __restrict__ w2,
                                                  unsigned short* __restrict__ Bt2) {
  int idx = blockIdx.x * 256 + threadIdx.x;   // CPAD2*128 total
  int cp = idx >> 7, k = idx & 127;
  int c_src = cp_to_src(cp);
  Bt2[idx] = (c_src >= 0) ? f2h(w2[(size_t)k * WTOT + c_src]) : (unsigned short)0;
}

// ---------------- K1: h = relu(edge_attr @ fc_w1 + b1) -> fp16 [EPAD][128] ------
__global__ __launch_bounds__(256) void k_fc1(const float* __restrict__ ea,
                                             const float* __restrict__ w1,
                                             const float* __restrict__ b1,
                                             unsigned short* __restrict__ hbf) {
  __shared__ float sT[128][36];
  int tid = threadIdx.x;
  int e0 = blockIdx.x * 32;
  for (int i = tid; i < 32 * 128; i += 256) {
    int el = i >> 7, k = i & 127;
    int e = e0 + el;
    sT[k][el] = (e < NEDGE) ? ea[(size_t)e * 128 + k] : 0.f;
  }
  __syncthreads();
  int cg = tid & 31;
  int eg = tid >> 5;
  float acc[4][4] = {};
  #pragma unroll 4
  for (int k = 0; k < 128; ++k) {
    float4 a = *(const float4*)&sT[k][eg * 4];
    float4 w = *(const float4*)&w1[k * 128 + cg * 4];
    float av[4] = {a.x, a.y, a.z, a.w};
    float wv[4] = {w.x, w.y, w.z, w.w};
    #pragma unroll
    for (int ii = 0; ii < 4; ++ii)
      #pragma unroll
      for (int jj = 0; jj < 4; ++jj)
        acc[ii][jj] += av[ii] * wv[jj];
  }
  float bb[4];
  #pragma unroll
  for (int jj = 0; jj < 4; ++jj) bb[jj] = b1[cg * 4 + jj];
  #pragma unroll
  for (int ii = 0; ii < 4; ++ii) {
    int e = e0 + eg * 4 + ii;
    bool val = e < NEDGE;
    unsigned short h4[4];
    #pragma unroll
    for (int jj = 0; jj < 4; ++jj) {
      float r = val ? fmaxf(acc[ii][jj] + bb[jj], 0.f) : 0.f;
      h4[jj] = f2h(r);
    }
    uint2 pk;
    pk.x = (unsigned)h4[0] | ((unsigned)h4[1] << 16);
    pk.y = (unsigned)h4[2] | ((unsigned)h4[3] << 16);
    *(uint2*)(hbf + (size_t)e * 128 + cg * 4) = pk;
  }
}

// ---------------- K3: fused GEMM + tensor product -------------------------------
// 4 waves/block, 64 edges/block. 78 phases x 3 tiles; double-buffered 12KB
// groups via global_load_lds.
// Head wait is vmcnt(0): correctness does NOT depend on counting VMEM ops
// (compiler-inserted scratch traffic broke counted vmcnt(3) in r4-r7).
// Loop body uses only NAMED scalars (no address-taken arrays) to avoid scratch.
__global__ __launch_bounds__(256, 3) void k_tp(const unsigned short* __restrict__ hbf,
                                               const unsigned short* __restrict__ Bt2,
                                               const float* __restrict__ fb2,
                                               const int* __restrict__ eidx,
                                               const float* __restrict__ node_attr,
                                               const float* __restrict__ esh,
                                               unsigned long long* __restrict__ summed,
                                               unsigned* __restrict__ cnt) {
  __shared__ half8    bufB[1536];        // 2 groups x 3 tiles x 4KB = 24576 B
  __shared__ float    sFT[48][64];       // transposed s: 12288 B (broadcast reads)
  __shared__ float    vFL[64][30];       // 7680 B
  __shared__ _Float16 b2pH[CPAD2];       // 7488 B
  __shared__ float    p0FL[64], q0FL[64];
  __shared__ float    sh1nL[64][3];
  __shared__ int      srcL[64], dstL[64];
  // total LDS = 53,824 B -> 3 blocks/CU

  const int tid  = threadIdx.x;
  const int wid  = tid >> 6;
  const int lane = tid & 63;
  const int col  = lane & 15;
  const int quad = lane >> 4;
  const int e0   = blockIdx.x * 64;
  const int elb  = wid * 16 + quad * 4;

  if (tid < 64) {
    int eg = e0 + tid;
    bool val = eg < NEDGE;
    srcL[tid] = val ? eidx[eg] : -1;
    dstL[tid] = val ? eidx[NEDGE + eg] : -1;
    float sh0 = 0.f, s1x = 0.f, s1y = 0.f, s1z = 0.f;
    if (val) {
      float4 s4 = *(const float4*)&esh[(size_t)eg * 4];
      sh0 = s4.x; s1x = s4.y; s1y = s4.z; s1z = s4.w;
    }
    p0FL[tid] = sh0 * NORM0;
    q0FL[tid] = sh0 * NORM1;
    sh1nL[tid][0] = s1x * NORM1; sh1nL[tid][1] = s1y * NORM1; sh1nL[tid][2] = s1z * NORM1;
  }
  for (int i = tid; i < CPAD2; i += 256) {
    int c_src = cp_to_src(i);
    b2pH[i] = (c_src >= 0) ? (_Float16)fb2[c_src] : (_Float16)0.f;
  }
  __syncthreads();
  for (int i = tid; i < 64 * NATT; i += 256) {
    int el = i / NATT, a = i % NATT;
    int dst = dstL[el];
    float x = (dst >= 0) ? node_attr[(size_t)dst * NATT + a] : 0.f;
    if (a < NS) sFT[a][el] = x; else vFL[el][a - NS] = x;
  }
  __syncthreads();

  // A fragments for this wave's 16 edges (full K=128)
  half8 aF0, aF1, aF2, aF3;
  {
    const half8* hp = (const half8*)hbf;
    size_t arow = (size_t)(e0 + wid * 16 + col) * 16;
    aF0 = hp[arow + 0 * 4 + quad];
    aF1 = hp[arow + 1 * 4 + quad];
    aF2 = hp[arow + 2 * 4 + quad];
    aF3 = hp[arow + 3 * 4 + quad];
  }
  float p0v[4];
  #pragma unroll
  for (int r = 0; r < 4; ++r) p0v[r] = p0FL[elb + r];

  // Staging: dest linear by tid within 4KB tile; source pre-swizzled so the
  // swizzled ds_read below is conflict-spread (both-sides rule).
  const char* bt2c = (const char*)Bt2;
  const int colS = tid >> 4, k8sS = tid & 15;
  const size_t gOff = (size_t)(colS * 16 + (k8sS ^ colS)) * 16;

  #define STAGE3(G) do {                                                           \
    int _t0 = (G) * 3;                                                             \
    char* _db = (char*)bufB + ((G) & 1) * 12288 + wid * 1024;                      \
    _Pragma("unroll")                                                              \
    for (int _t = 0; _t < 3; ++_t)                                                 \
      __builtin_amdgcn_global_load_lds(                                            \
        (const __attribute__((address_space(1))) void*)(bt2c + (size_t)(_t0 + _t) * 4096 + gOff), \
        (__attribute__((address_space(3))) void*)(_db + _t * 4096), 16, 0, 0);     \
  } while (0)

  STAGE3(0); STAGE3(1);

  float acc0[4][3] = {};
  float t1a[4] = {};
  float t3a[4][3] = {};

  // invariant ds_read sub-indices
  const int k0 = (0 * 4 + quad) ^ col;
  const int k1 = (1 * 4 + quad) ^ col;
  const int k2 = (2 * 4 + quad) ^ col;
  const int k3 = (3 * 4 + quad) ^ col;
  const int cb = col * 16;

  #pragma unroll 1
  for (int p = 0; p < NGRP; ++p) {
    // drain-all + barrier: all staged groups (p and p+1) are in LDS, regardless
    // of any compiler-generated VMEM ops. Fused blob: nothing between wait/bar.
    asm volatile("s_waitcnt vmcnt(0)\n\ts_barrier" ::: "memory");

    const int bb = ((p & 1) << 9) + ((p & 1) << 8) + cb;   // (p&1)*768 + col*16
    half8 b00 = bufB[bb +   0 + k0], b01 = bufB[bb +   0 + k1],
          b02 = bufB[bb +   0 + k2], b03 = bufB[bb +   0 + k3];
    half8 b10 = bufB[bb + 256 + k0], b11 = bufB[bb + 256 + k1],
          b12 = bufB[bb + 256 + k2], b13 = bufB[bb + 256 + k3];
    half8 b20 = bufB[bb + 512 + k0], b21 = bufB[bb + 512 + k1],
          b22 = bufB[bb + 512 + k2], b23 = bufB[bb + 512 + k3];

    __builtin_amdgcn_s_setprio(1);
    f32x4 m0 = {0.f, 0.f, 0.f, 0.f};
    f32x4 m1 = {0.f, 0.f, 0.f, 0.f};
    f32x4 m2 = {0.f, 0.f, 0.f, 0.f};
    m0 = __builtin_amdgcn_mfma_f32_16x16x32_f16(aF0, b00, m0, 0, 0, 0);
    m1 = __builtin_amdgcn_mfma_f32_16x16x32_f16(aF0, b10, m1, 0, 0, 0);
    m2 = __builtin_amdgcn_mfma_f32_16x16x32_f16(aF0, b20, m2, 0, 0, 0);
    m0 = __builtin_amdgcn_mfma_f32_16x16x32_f16(aF1, b01, m0, 0, 0, 0);
    m1 = __builtin_amdgcn_mfma_f32_16x16x32_f16(aF1, b11, m1, 0, 0, 0);
    m2 = __builtin_amdgcn_mfma_f32_16x16x32_f16(aF1, b21, m2, 0, 0, 0);
    m0 = __builtin_amdgcn_mfma_f32_16x16x32_f16(aF2, b02, m0, 0, 0, 0);
    m1 = __builtin_amdgcn_mfma_f32_16x16x32_f16(aF2, b12, m1, 0, 0, 0);
    m2 = __builtin_amdgcn_mfma_f32_16x16x32_f16(aF2, b22, m2, 0, 0, 0);
    m0 = __builtin_amdgcn_mfma_f32_16x16x32_f16(aF3, b03, m0, 0, 0, 0);
    m1 = __builtin_amdgcn_mfma_f32_16x16x32_f16(aF3, b13, m1, 0, 0, 0);
    m2 = __builtin_amdgcn_mfma_f32_16x16x32_f16(aF3, b23, m2, 0, 0, 0);
    __builtin_amdgcn_s_setprio(0);

    // all waves done reading buf[p&1] before it is overwritten below
    asm volatile("s_waitcnt lgkmcnt(0)\n\ts_barrier" ::: "memory");
    if (p < NGRP - 2) STAGE3(p + 2);

    // ---- epilogue (named scalars only) ----
    float b2c0 = (float)b2pH[(p * 3 + 0) * 16 + col];
    float b2c1 = (float)b2pH[(p * 3 + 1) * 16 + col];
    float b2c2 = (float)b2pH[(p * 3 + 2) * 16 + col];
    if (p < 48) {                        // region A (w1), u = p
      #pragma unroll
      for (int r = 0; r < 4; ++r) {
        float sfac = sFT[p][elb + r] * p0v[r];
        acc0[r][0] += (m0[r] + b2c0) * sfac;
        acc0[r][1] += (m1[r] + b2c1) * sfac;
        acc0[r][2] += (m2[r] + b2c2) * sfac;
      }
    } else if (p < 58) {                 // region B (w4), u = p-48
      int u3 = (p - 48) * 3;
      #pragma unroll
      for (int r = 0; r < 4; ++r) {
        int el = elb + r;
        float dfac = (vFL[el][u3]     * sh1nL[el][0] +
                      vFL[el][u3 + 1] * sh1nL[el][1] +
                      vFL[el][u3 + 2] * sh1nL[el][2]) * INV_SQRT3;
        acc0[r][0] += (m0[r] + b2c0) * dfac;
        acc0[r][1] += (m1[r] + b2c1) * dfac;
        acc0[r][2] += (m2[r] + b2c2) * dfac;
      }
    } else if (p < 74) {                 // region C (w2), u = 3(p-58)+j
      int u0 = (p - 58) * 3;
      #pragma unroll
      for (int r = 0; r < 4; ++r) {
        int el = elb + r;
        t1a[r] += (m0[r] + b2c0) * sFT[u0][el]
                + (m1[r] + b2c1) * sFT[u0 + 1][el]
                + (m2[r] + b2c2) * sFT[u0 + 2][el];
      }
    } else {                             // region D (w3), T = 3p+j, guard pad
      int ub = (p - 74) * 3;
      int T0 = p * 3;
      #pragma unroll
      for (int r = 0; r < 4; ++r) {
        int el = elb + r;
        {
          float w = m0[r] + b2c0;
          t3a[r][0] += w * vFL[el][(ub + 0) * 3 + 0];
          t3a[r][1] += w * vFL[el][(ub + 0) * 3 + 1];
          t3a[r][2] += w * vFL[el][(ub + 0) * 3 + 2];
        }
        if (T0 + 1 < NTILE) {
          float w = m1[r] + b2c1;
          t3a[r][0] += w * vFL[el][(ub + 1) * 3 + 0];
          t3a[r][1] += w * vFL[el][(ub + 1) * 3 + 1];
          t3a[r][2] += w * vFL[el][(ub + 1) * 3 + 2];
        }
        if (T0 + 2 < NTILE) {
          float w = m2[r] + b2c2;
          t3a[r][0] += w * vFL[el][(ub + 2) * 3 + 0];
          t3a[r][1] += w * vFL[el][(ub + 2) * 3 + 1];
          t3a[r][2] += w * vFL[el][(ub + 2) * 3 + 2];
        }
      }
    }
  }
  #undef STAGE3

  // ---- Flush: registers -> global integer atomics (deterministic) ----
  #pragma unroll
  for (int r = 0; r < 4; ++r) {
    int el = elb + r;
    int src = srcL[el];
    if (src < 0) continue;
    unsigned long long* dp = &summed[(size_t)src * NATT];
    #pragma unroll
    for (int j = 0; j < 3; ++j)
      atomFx(dp + j * 16 + col, acc0[r][j]);
    if (col < 10) {
      float q0 = q0FL[el];
      #pragma unroll
      for (int i = 0; i < 3; ++i)
        atomFx(dp + NS + col * 3 + i,
               t1a[r] * sh1nL[el][i] + t3a[r][i] * q0);
    }
  }
  if (tid < 64 && srcL[tid] >= 0) atomicAdd(&cnt[srcL[tid]], 1u);
}

// ---------------- K4: mean over segment + residual, accumulate BN stats ---------
__global__ __launch_bounds__(256) void k_node(const unsigned long long* __restrict__ summed,
                                              const unsigned* __restrict__ cnt,
                                              const float* __restrict__ node_attr,
                                              float* __restrict__ outp,
                                              unsigned long long* __restrict__ stats) {
  __shared__ unsigned long long ls[NS], lq[NS], lv[NV];
  int tid = threadIdx.x;
  if (tid < NS) { ls[tid] = 0ull; lq[tid] = 0ull; }
  if (tid < NV) lv[tid] = 0ull;
  __syncthreads();
  int i = blockIdx.x * 256 + tid;
  if (i < NNODE * NATT) {
    int row = i / NATT, colc = i % NATT;
    long long sv = (long long)summed[i];
    float sum = (float)((double)sv * FXSI);
    float x = sum / fmaxf((float)cnt[row], 1.f) + node_attr[i];
    outp[i] = x;
    if (colc < NS) {
      atomicAdd(&ls[colc], (unsigned long long)(long long)rintf(x * FXS));
      atomicAdd(&lq[colc], (unsigned long long)(long long)rintf(x * x * FXQ));
    } else {
      atomicAdd(&lv[(colc - NS) / 3], (unsigned long long)(long long)rintf(x * x * FXQ));
    }
  }
  __syncthreads();
  if (tid < NS) { atomicAdd(&stats[tid], ls[tid]); atomicAdd(&stats[NS + tid], lq[tid]); }
  if (tid < NV) atomicAdd(&stats[96 + tid], lv[tid]);
}

// ---------------- K5: batch norm apply ------------------------------------------
__global__ __launch_bounds__(256) void k_bn(const float* __restrict__ outp,
                                            const unsigned long long* __restrict__ stats,
                                            const float* __restrict__ bnw,
                                            const float* __restrict__ bnb,
                                            float* __restrict__ out) {
  int i = blockIdx.x * 256 + threadIdx.x;
  if (i >= NNODE * NATT) return;
  int colc = i % NATT;
  float x = outp[i];
  float r;
  if (colc < NS) {
    float mean = (float)((double)(long long)stats[colc] * (FXSI / NNODE));
    float ex2  = (float)((double)(long long)stats[NS + colc] * (FXQI / NNODE));
    float var  = ex2 - mean * mean;
    r = (x - mean) * rsqrtf(var + EPSV) * bnw[colc] + bnb[colc];
  } else {
    int u = (colc - NS) / 3;
    float vn = (float)((double)(long long)stats[96 + u] * (FXQI / (3.0 * NNODE)));
    r = x * rsqrtf(vn + EPSV) * bnw[NS + u];
  }
  out[i] = r;
}

extern "C" void kernel_launch(void* const* d_in, const int* in_sizes, int n_in,
                              void* d_out, int out_size, void* d_ws, size_t ws_size,
                              hipStream_t stream) {
  const float* node_attr = (const float*)d_in[0];
  const int*   eidx      = (const int*)d_in[1];
  const float* edge_attr = (const float*)d_in[2];
  const float* esh       = (const float*)d_in[3];
  const float* fw1       = (const float*)d_in[4];
  const float* fb1       = (const float*)d_in[5];
  const float* fw2       = (const float*)d_in[6];
  const float* fb2       = (const float*)d_in[7];
  const float* bnw       = (const float*)d_in[8];
  const float* bnb       = (const float*)d_in[9];
  float* out = (float*)d_out;

  char* ws = (char*)d_ws;
  // layout (bytes) -- total 20,050,752:
  //   Bt2    @ 0        : CPAD2*128*2 =    958,464   (dead after k_tp)
  //   hbf    @ 958464   : EPAD*128*2  = 12,812,288   (dead after k_tp)
  //   summed @ 13770752 : N*78*8     =   6,240,000   (i64 Q31)
  //   cnt    @ 20010752 : N*4        =      40,000   (u32)
  //   outp   @ 0        : N*78*4     =   3,120,000   (reuses Bt2+hbf head, after k_tp)
  //   stats  @ 3120000  : 128*8      =       1,024   (inside dead hbf, after k_tp)
  unsigned short*     Bt2    = (unsigned short*)(ws + 0);
  unsigned short*     hbf    = (unsigned short*)(ws + 958464);
  unsigned long long* summed = (unsigned long long*)(ws + 13770752);
  unsigned*           cnt    = (unsigned*)(ws + 20010752);
  float*              outp   = (float*)(ws + 0);
  unsigned long long* stats  = (unsigned long long*)(ws + 3120000);

  hipMemsetAsync(ws + 13770752, 0, 6240000 + 40000, stream);   // summed + cnt

  k_prep_bt2<<<(CPAD2 * 128) / 256, 256, 0, stream>>>(fw2, Bt2);
  k_fc1<<<EPAD / 32, 256, 0, stream>>>(edge_attr, fw1, fb1, hbf);
  k_tp<<<EPAD / 64, 256, 0, stream>>>(hbf, Bt2, fb2, eidx, node_attr, esh, summed, cnt);
  hipMemsetAsync(ws + 3120000, 0, 1024, stream);
  int nelem_blocks = (NNODE * NATT + 255) / 256;
  k_node<<<nelem_blocks, 256, 0, stream>>>(summed, cnt, node_attr, outp, stats);
  k_bn<<<nelem_blocks, 256, 0, stream>>>(outp, stats, bnw, bnb, out);
}